// Round 1
// baseline (218.854 us; speedup 1.0000x reference)
//
#include <hip/hip_runtime.h>

using bf16x8 = __attribute__((ext_vector_type(8))) short;
using f32x4  = __attribute__((ext_vector_type(4))) float;
using f32x16 = __attribute__((ext_vector_type(16))) float;
using u32x4  = __attribute__((ext_vector_type(4))) unsigned int;

#define NPIX 4096
#define CCH  256

__device__ __forceinline__ unsigned short f2bf(float f) {
  unsigned int u = __builtin_bit_cast(unsigned int, f);
  u += 0x7FFFu + ((u >> 16) & 1u);
  return (unsigned short)(u >> 16);
}

__device__ __forceinline__ float bfu(unsigned short h) {
  unsigned int u = ((unsigned int)h) << 16;
  return __builtin_bit_cast(float, u);
}

__device__ __forceinline__ unsigned int pack2(float a, float b) {
  return (unsigned int)f2bf(a) | ((unsigned int)f2bf(b) << 16);
}

__device__ __forceinline__ void gld_lds16(const void* g, void* l) {
  __builtin_amdgcn_global_load_lds(
      (const __attribute__((address_space(1))) unsigned int*)g,
      (__attribute__((address_space(3))) unsigned int*)l, 16, 0, 0);
}

// ---------------- W conversion fp32 -> bf16, [3][256][256] ----------------
__global__ __launch_bounds__(256) void convert_w_kernel(
    const float* __restrict__ Wb, const float* __restrict__ Wc,
    const float* __restrict__ Wd, unsigned short* __restrict__ Wbf) {
  const int mat = blockIdx.y;
  const float* src = (mat == 0) ? Wb : (mat == 1) ? Wc : Wd;
  int i = (blockIdx.x * 256 + threadIdx.x) * 4;
  float4 v = *reinterpret_cast<const float4*>(src + i);
  uint2 o;
  o.x = pack2(v.x, v.y);
  o.y = pack2(v.z, v.w);
  *reinterpret_cast<uint2*>(Wbf + mat * 65536 + i) = o;
}

// ---------------- fused transpose + 3 projections (coalesced stores) ----------
__global__ __launch_bounds__(256, 2) void fused_proj_kernel(
    const float* __restrict__ x, const unsigned short* __restrict__ Wbf,
    const float* __restrict__ bb, const float* __restrict__ bc,
    const float* __restrict__ bd, unsigned short* __restrict__ Q,
    unsigned short* __restrict__ K, unsigned short* __restrict__ Vt) {
  __shared__ __align__(16) float tile[64][65];   // phase-1 scratch + bounce
  __shared__ __align__(16) char xsub[32768];
  char* bounce = (char*)tile;

  const int tid = threadIdx.x;
  const int wid = tid >> 6, lane = tid & 63;
  const int l31 = lane & 31, hi = lane >> 5;
  const int lt = blockIdx.x, n = blockIdx.y;

  // ---- phase 1: x[n][c][lt*64..] -> bf16 subtiles ----
  #pragma unroll 1
  for (int ct = 0; ct < 4; ++ct) {
    const float* xg = x + ((size_t)(n * CCH + ct * 64)) * NPIX + lt * 64;
    #pragma unroll
    for (int it = 0; it < 4; ++it) {
      int row = (tid >> 4) + it * 16;
      int col = (tid & 15) * 4;
      float4 v = *reinterpret_cast<const float4*>(xg + (size_t)row * NPIX + col);
      tile[row][col] = v.x; tile[row][col + 1] = v.y;
      tile[row][col + 2] = v.z; tile[row][col + 3] = v.w;
    }
    __syncthreads();
    #pragma unroll
    for (int it = 0; it < 2; ++it) {
      int idx = tid + it * 256;
      int l = idx >> 3;
      int ch = (idx & 7) * 8;
      int c = ct * 64 + ch;
      uint4 o;
      o.x = pack2(tile[ch + 0][l], tile[ch + 1][l]);
      o.y = pack2(tile[ch + 2][l], tile[ch + 3][l]);
      o.z = pack2(tile[ch + 4][l], tile[ch + 5][l]);
      o.w = pack2(tile[ch + 6][l], tile[ch + 7][l]);
      int addr = (l >> 5) * 16384 + (c >> 4) * 1024 + ((c >> 3) & 1) * 512 + (l & 31) * 16;
      *reinterpret_cast<uint4*>(xsub + addr) = o;
    }
    __syncthreads();
  }

  // ---- phase 2: wave = o-quarter [wid*64, wid*64+64) ----
  const int o0a = wid * 64, o0b = wid * 64 + 32;
  const size_t pixrow = (size_t)n * NPIX + lt * 64;

  #pragma unroll 1
  for (int mat = 0; mat < 3; ++mat) {
    const unsigned short* W = Wbf + mat * 65536;
    const float* bias = (mat == 0) ? bb : (mat == 1) ? bc : bd;
    f32x16 a00, a01, a10, a11;  // [oi][pix-half]
    #pragma unroll
    for (int e = 0; e < 16; ++e) { a00[e] = 0.f; a01[e] = 0.f; a10[e] = 0.f; a11[e] = 0.f; }
    #pragma unroll
    for (int c0 = 0; c0 < 16; ++c0) {
      bf16x8 x0 = *reinterpret_cast<const bf16x8*>(xsub + c0 * 1024 + lane * 16);
      bf16x8 x1 = *reinterpret_cast<const bf16x8*>(xsub + 16384 + c0 * 1024 + lane * 16);
      bf16x8 w0 = *reinterpret_cast<const bf16x8*>(W + (o0a + l31) * CCH + c0 * 16 + hi * 8);
      bf16x8 w1 = *reinterpret_cast<const bf16x8*>(W + (o0b + l31) * CCH + c0 * 16 + hi * 8);
      if (mat < 2) {
        a00 = __builtin_amdgcn_mfma_f32_32x32x16_bf16(w0, x0, a00, 0, 0, 0);
        a01 = __builtin_amdgcn_mfma_f32_32x32x16_bf16(w0, x1, a01, 0, 0, 0);
        a10 = __builtin_amdgcn_mfma_f32_32x32x16_bf16(w1, x0, a10, 0, 0, 0);
        a11 = __builtin_amdgcn_mfma_f32_32x32x16_bf16(w1, x1, a11, 0, 0, 0);
      } else {
        a00 = __builtin_amdgcn_mfma_f32_32x32x16_bf16(x0, w0, a00, 0, 0, 0);
        a01 = __builtin_amdgcn_mfma_f32_32x32x16_bf16(x1, w0, a01, 0, 0, 0);
        a10 = __builtin_amdgcn_mfma_f32_32x32x16_bf16(x0, w1, a10, 0, 0, 0);
        a11 = __builtin_amdgcn_mfma_f32_32x32x16_bf16(x1, w1, a11, 0, 0, 0);
      }
    }
    if (mat < 2) {
      unsigned short* dst = (mat == 0) ? Q : K;
      #pragma unroll 1
      for (int ph = 0; ph < 2; ++ph) {
        __syncthreads();
        const f32x16& A0 = ph ? a01 : a00;
        const f32x16& A1 = ph ? a11 : a10;
        const int swz = (l31 & 15) << 4;
        #pragma unroll
        for (int r2 = 0; r2 < 8; ++r2) {
          const int r = r2 * 2;
          const int od = (r & 3) + 8 * (r >> 2) + 4 * hi;
          const int oa = o0a + od, ob = o0b + od;
          *reinterpret_cast<unsigned int*>(bounce + ((l31 * 512 + oa * 2) ^ swz)) =
              pack2(A0[r] + bias[oa], A0[r + 1] + bias[oa + 1]);
          *reinterpret_cast<unsigned int*>(bounce + ((l31 * 512 + ob * 2) ^ swz)) =
              pack2(A1[r] + bias[ob], A1[r + 1] + bias[ob + 1]);
        }
        __syncthreads();
        const int dp = tid >> 3, obase = (tid & 7) * 32;
        const int dswz = (dp & 15) << 4;
        char* gout = (char*)(dst + (pixrow + ph * 32 + dp) * CCH + obase);
        #pragma unroll
        for (int k = 0; k < 4; ++k) {
          u32x4 v = *reinterpret_cast<const u32x4*>(
              bounce + ((dp * 512 + obase * 2 + k * 16) ^ dswz));
          *reinterpret_cast<u32x4*>(gout + k * 16) = v;
        }
      }
    } else {
      #pragma unroll 1
      for (int os = 0; os < 2; ++os) {
        __syncthreads();
        if ((wid >> 1) == os) {
          const int ola = o0a + l31 - os * 128, olb = o0b + l31 - os * 128;
          const float bva = bias[o0a + l31], bvb = bias[o0b + l31];
          const int sza = (ola & 7) << 4, szb = (olb & 7) << 4;
          #pragma unroll
          for (int r2 = 0; r2 < 8; ++r2) {
            const int r = r2 * 2;
            const int pd = (r & 3) + 8 * (r >> 2) + 4 * hi;
            *reinterpret_cast<unsigned int*>(bounce + ((ola * 128 + pd * 2) ^ sza)) =
                pack2(a00[r] + bva, a00[r + 1] + bva);
            *reinterpret_cast<unsigned int*>(bounce + ((ola * 128 + (pd + 32) * 2) ^ sza)) =
                pack2(a01[r] + bva, a01[r + 1] + bva);
            *reinterpret_cast<unsigned int*>(bounce + ((olb * 128 + pd * 2) ^ szb)) =
                pack2(a10[r] + bvb, a10[r + 1] + bvb);
            *reinterpret_cast<unsigned int*>(bounce + ((olb * 128 + (pd + 32) * 2) ^ szb)) =
                pack2(a11[r] + bvb, a11[r + 1] + bvb);
          }
        }
        __syncthreads();
        const int ol = tid >> 1, pb0 = (tid & 1) * 32;
        const int vswz = (ol & 7) << 4;
        char* gout = (char*)(Vt + ((size_t)(n * CCH + os * 128 + ol)) * NPIX + lt * 64 + pb0);
        #pragma unroll
        for (int k = 0; k < 4; ++k) {
          u32x4 v = *reinterpret_cast<const u32x4*>(
              bounce + ((ol * 128 + pb0 * 2 + k * 16) ^ vswz));
          *reinterpret_cast<u32x4*>(gout + k * 16) = v;
        }
      }
    }
  }
}

// ---------------- attention partial: one j-half per block ----------------
// 4 waves x 32 q; KVBLK=32, 64 iters, dbuf 2x32KB -> 2 blocks/CU.
// T3/T4 counted-vmcnt pipeline: two raw barriers per iter, never vmcnt(0)
// in-loop. Each wave stages 4 K-chunks (phase A) + 4 V-chunks (phase B).
// Schedule per iter t (par = t&1):
//   issue K(t+1)->par^1 | vmcnt(8) [K(t) done] | barrier | QK^T
//   issue V(t+1)->par^1 | softmax | vmcnt(8) [V(t) done] | barrier | PV
// Buffer safety: overwrite-issue of each par^1 buffer is >=1 barrier after
// all waves' reads of it (K read phase A(t-1) < barrier B(t-1) < issue @ t;
// V read phase B(t-1) < barrier A(t) < issue after QK^T(t)).
__global__ __launch_bounds__(256, 2) void attn_part_kernel(
    const unsigned short* __restrict__ Q, const unsigned short* __restrict__ K,
    const unsigned short* __restrict__ Vt, unsigned short* __restrict__ Opart,
    float* __restrict__ lsumbuf) {
  __shared__ __align__(16) char smem[65536];

  const int tid = threadIdx.x;
  const int wid = tid >> 6;
  const int lane = tid & 63;
  const int l31 = lane & 31;
  const int hi = lane >> 5;
  const int lofs = lane << 4;
  const int blk = blockIdx.x;
  const int n = blk & 7;
  const int t2 = blk >> 3;
  const int half = t2 & 1;
  const int qb = t2 >> 1;
  const int q0 = qb * 128 + wid * 32;

  const unsigned short* Qg = Q + (size_t)n * NPIX * CCH;
  const char* Kg = (const char*)(K + ((size_t)n * NPIX + half * 2048) * CCH);
  const char* Vg = (const char*)(Vt + (size_t)n * CCH * NPIX + half * 2048);

  bf16x8 qf[16];
  #pragma unroll
  for (int c0 = 0; c0 < 16; ++c0)
    qf[c0] = *reinterpret_cast<const bf16x8*>(
        Qg + (size_t)(q0 + l31) * CCH + c0 * 16 + hi * 8);

  f32x16 oacc[8];
  #pragma unroll
  for (int i = 0; i < 8; ++i)
    #pragma unroll
    for (int e = 0; e < 16; ++e) oacc[i][e] = 0.f;
  float lsum = 0.f;

  // per-wave staging offsets: 4 K-chunks + 4 V-chunks (chunk = wid*4+g)
  int soffK[4], soffV[4];
  #pragma unroll
  for (int g = 0; g < 4; ++g) {
    const int s = wid * 4 + g;
    soffK[g] = l31 * 512 + s * 32 + hi * 16;
    const int cb = s >> 1, kk2 = s & 1;
    soffV[g] = (cb * 32 + l31) * 8192 + (kk2 * 16 + hi * 8) * 2;
  }

  auto STAGE_K = [&](int par_, int adv) {
    #pragma unroll
    for (int g = 0; g < 4; ++g)
      gld_lds16(Kg + (size_t)soffK[g] + (size_t)adv,
                smem + par_ * 32768 + (wid * 4 + g) * 1024);
  };
  auto STAGE_V = [&](int par_, int adv) {
    #pragma unroll
    for (int g = 0; g < 4; ++g)
      gld_lds16(Vg + (size_t)soffV[g] + (size_t)adv,
                smem + par_ * 32768 + 16384 + (wid * 4 + g) * 1024);
  };

  // prologue: stage tile 0 (4 K loads then 4 V loads in flight)
  STAGE_K(0, 0);
  STAGE_V(0, 0);

  #pragma unroll 1
  for (int t = 0; t < 64; ++t) {
    const int par = t & 1;
    const char* kb = smem + par * 32768;
    const char* vb = kb + 16384;
    const int tn = (t + 1) & 63;   // wrap keeps counts uniform; t=63 prefetch is junk-but-in-bounds

    // issue K(t+1); then wait K(t) landed (V(t)+K(t+1) = 8 younger stay in flight)
    STAGE_K(par ^ 1, tn * 16384);
    __builtin_amdgcn_sched_barrier(0);
    asm volatile("s_waitcnt vmcnt(8)" ::: "memory");
    __builtin_amdgcn_s_barrier();
    __builtin_amdgcn_sched_barrier(0);

    f32x16 S;
    #pragma unroll
    for (int e = 0; e < 16; ++e) S[e] = 0.f;
    __builtin_amdgcn_s_setprio(1);
    #pragma unroll
    for (int c0 = 0; c0 < 16; ++c0) {
      bf16x8 kf = *reinterpret_cast<const bf16x8*>(kb + c0 * 1024 + lofs);
      S = __builtin_amdgcn_mfma_f32_32x32x16_bf16(kf, qf[c0], S, 0, 0, 0);
    }
    __builtin_amdgcn_s_setprio(0);

    // issue V(t+1) now; its latency is covered by softmax below
    STAGE_V(par ^ 1, tn * 64);

    // ---- fixed-offset softmax: P = exp2(S*log2e - 101), pack via cvt_pk ----
    float rsum = 0.f;
    unsigned int pw[8];
    #pragma unroll
    for (int i = 0; i < 8; ++i) {
      float p0 = exp2f(fmaf(S[2 * i],     1.44269504f, -101.0f));
      float p1 = exp2f(fmaf(S[2 * i + 1], 1.44269504f, -101.0f));
      rsum += p0 + p1;
      unsigned int r;
      asm("v_cvt_pk_bf16_f32 %0, %1, %2" : "=v"(r) : "v"(p0), "v"(p1));
      pw[i] = r;
    }
    lsum += rsum;

    // ---- P re-layout via permlane32_swap ----
    unsigned int s0a = pw[0], s0b = pw[2];
    unsigned int s1a = pw[1], s1b = pw[3];
    unsigned int s2a = pw[4], s2b = pw[6];
    unsigned int s3a = pw[5], s3b = pw[7];
    asm volatile("v_permlane32_swap_b32 %0, %1" : "+v"(s0a), "+v"(s0b));
    asm volatile("v_permlane32_swap_b32 %0, %1" : "+v"(s1a), "+v"(s1b));
    asm volatile("v_permlane32_swap_b32 %0, %1" : "+v"(s2a), "+v"(s2b));
    asm volatile("v_permlane32_swap_b32 %0, %1" : "+v"(s3a), "+v"(s3b));
    u32x4 f0, f1;
    f0[0] = s0a; f0[1] = s1a; f0[2] = s0b; f0[3] = s1b;
    f1[0] = s2a; f1[1] = s3a; f1[2] = s2b; f1[3] = s3b;
    bf16x8 pa0 = __builtin_bit_cast(bf16x8, f0);
    bf16x8 pa1 = __builtin_bit_cast(bf16x8, f1);

    // wait V(t) landed (K(t+1)+V(t+1) = 8 younger stay in flight)
    __builtin_amdgcn_sched_barrier(0);
    asm volatile("s_waitcnt vmcnt(8)" ::: "memory");
    __builtin_amdgcn_s_barrier();
    __builtin_amdgcn_sched_barrier(0);

    __builtin_amdgcn_s_setprio(1);
    #pragma unroll
    for (int cb = 0; cb < 8; ++cb) {
      bf16x8 v0 = *reinterpret_cast<const bf16x8*>(vb + (cb * 2 + 0) * 1024 + lofs);
      oacc[cb] = __builtin_amdgcn_mfma_f32_32x32x16_bf16(pa0, v0, oacc[cb], 0, 0, 0);
      bf16x8 v1 = *reinterpret_cast<const bf16x8*>(vb + (cb * 2 + 1) * 1024 + lofs);
      oacc[cb] = __builtin_amdgcn_mfma_f32_32x32x16_bf16(pa1, v1, oacc[cb], 0, 0, 0);
    }
    __builtin_amdgcn_s_setprio(0);
  }

  // drain the junk wrap-around prefetch DMA before block exit (LDS reuse safety)
  asm volatile("s_waitcnt vmcnt(0)" ::: "memory");

  lsum += __shfl_xor(lsum, 32);
  char* slab = (char*)Opart + (size_t)blk * 65536;
  #pragma unroll
  for (int cb = 0; cb < 8; ++cb) {
    u32x4 u0, u1;
    u0[0] = pack2(oacc[cb][0],  oacc[cb][1]);
    u0[1] = pack2(oacc[cb][2],  oacc[cb][3]);
    u0[2] = pack2(oacc[cb][4],  oacc[cb][5]);
    u0[3] = pack2(oacc[cb][6],  oacc[cb][7]);
    u1[0] = pack2(oacc[cb][8],  oacc[cb][9]);
    u1[1] = pack2(oacc[cb][10], oacc[cb][11]);
    u1[2] = pack2(oacc[cb][12], oacc[cb][13]);
    u1[3] = pack2(oacc[cb][14], oacc[cb][15]);
    *reinterpret_cast<u32x4*>(slab + (cb * 2 + 0) * 4096 + tid * 16) = u0;
    *reinterpret_cast<u32x4*>(slab + (cb * 2 + 1) * 4096 + tid * 16) = u1;
  }
  if (hi == 0) lsumbuf[blk * 128 + wid * 32 + l31] = lsum;
}

// ---------------- merge halves + normalize + residual + transpose ----------------
// grid 256 = (n, qb); 512 threads (8 waves -> better latency hiding).
// Thread (pr8 = tid>>6): qsub = pr8&3, cb-half = pr8>>2.
__global__ __launch_bounds__(512) void merge_kernel(
    const unsigned short* __restrict__ Opart, const float* __restrict__ lsumbuf,
    const float* __restrict__ x, const float* __restrict__ alpha_p,
    float* __restrict__ out) {
  __shared__ float T[32768];   // [c 0..255][q' 0..127], elem = c*128 + (q'^(c&28))
  __shared__ float Lq[128];

  const int tid = threadIdx.x;
  const int pr8 = tid >> 6;
  const int lane = tid & 63;
  const int l31 = lane & 31;
  const int hi = lane >> 5;
  const int qsub = pr8 & 3;
  const int cbh = pr8 >> 2;
  const int atid = qsub * 64 + lane;    // matching attn-slab thread index
  const int m = blockIdx.x;
  const int n = m & 7;
  const int qb = m >> 3;
  const int blkA = n + 8 * (0 + 2 * qb);
  const int blkB = n + 8 * (1 + 2 * qb);

  if (tid < 128)
    Lq[tid] = alpha_p[0] / (lsumbuf[blkA * 128 + tid] + lsumbuf[blkB * 128 + tid]);
  __syncthreads();

  const char* sa = (const char*)Opart + (size_t)blkA * 65536;
  const char* sb = (const char*)Opart + (size_t)blkB * 65536;

  #pragma unroll
  for (int cbi = 0; cbi < 4; ++cbi) {
    const int cb = cbh * 4 + cbi;
    const int c = cb * 32 + l31;
    const int swz = c & 28;
    #pragma unroll
    for (int h = 0; h < 2; ++h) {
      u32x4 a = *reinterpret_cast<const u32x4*>(sa + (cb * 2 + h) * 4096 + atid * 16);
      u32x4 b = *reinterpret_cast<const u32x4*>(sb + (cb * 2 + h) * 4096 + atid * 16);
      #pragma unroll
      for (int w = 0; w < 4; ++w) {
        const int r = h * 8 + w * 2;
        float v0 = bfu((unsigned short)(a[w] & 0xFFFF)) + bfu((unsigned short)(b[w] & 0xFFFF));
        float v1 = bfu((unsigned short)(a[w] >> 16)) + bfu((unsigned short)(b[w] >> 16));
        const int q0l = qsub * 32 + ((r) & 3) + 8 * ((r) >> 2) + 4 * hi;
        const int q1l = q0l + 1;
        T[c * 128 + (q0l ^ swz)] = v0 * Lq[q0l];
        T[c * 128 + (q1l ^ swz)] = v1 * Lq[q1l];
      }
    }
  }
  __syncthreads();

  // write out: 16 sweeps, 16 c-rows per sweep, float4 per thread
  const int l0 = (tid & 31) * 4;
  #pragma unroll 4
  for (int sw = 0; sw < 16; ++sw) {
    const int c = (tid >> 5) + sw * 16;
    const float* src = &T[c * 128 + (l0 ^ (c & 28))];
    float4 v = *reinterpret_cast<const float4*>(src);
    const size_t g = ((size_t)n * CCH + c) * NPIX + qb * 128 + l0;
    float4 xi = *reinterpret_cast<const float4*>(x + g);
    float4 o;
    o.x = v.x + xi.x; o.y = v.y + xi.y; o.z = v.z + xi.z; o.w = v.w + xi.w;
    *reinterpret_cast<float4*>(out + g) = o;
  }
}

extern "C" void kernel_launch(void* const* d_in, const int* in_sizes, int n_in,
                              void* d_out, int out_size, void* d_ws, size_t ws_size,
                              hipStream_t stream) {
  const float* x  = (const float*)d_in[0];
  const float* Wb = (const float*)d_in[1];
  const float* bb = (const float*)d_in[2];
  const float* Wc = (const float*)d_in[3];
  const float* bc = (const float*)d_in[4];
  const float* Wd = (const float*)d_in[5];
  const float* bd = (const float*)d_in[6];
  const float* alpha = (const float*)d_in[7];
  float* out = (float*)d_out;
  char* ws = (char*)d_ws;

  unsigned short* Wbf   = (unsigned short*)(ws);                //    393,216 B
  unsigned short* Q     = (unsigned short*)(ws + 393216);       // 16,777,216 B
  unsigned short* K     = (unsigned short*)(ws + 17170432);     // 16,777,216 B
  unsigned short* Vt    = (unsigned short*)(ws + 33947648);     // 16,777,216 B
  unsigned short* Opart = (unsigned short*)(ws + 50724864);     // 33,554,432 B
  float*          lsumb = (float*)(ws + 84279296);              //    262,144 B

  convert_w_kernel<<<dim3(64, 3), 256, 0, stream>>>(Wb, Wc, Wd, Wbf);
  fused_proj_kernel<<<dim3(64, 8), 256, 0, stream>>>(x, Wbf, bb, bc, bd, Q, K, Vt);
  attn_part_kernel<<<dim3(512), 256, 0, stream>>>(Q, K, Vt, Opart, lsumb);
  merge_kernel<<<dim3(256), 512, 0, stream>>>(Opart, lsumb, x, alpha, out);
}

// Round 2
// 217.792 us; speedup vs baseline: 1.0049x; 1.0049x over previous
//
#include <hip/hip_runtime.h>

using bf16x8 = __attribute__((ext_vector_type(8))) short;
using f32x4  = __attribute__((ext_vector_type(4))) float;
using f32x16 = __attribute__((ext_vector_type(16))) float;
using u32x4  = __attribute__((ext_vector_type(4))) unsigned int;

#define NPIX 4096
#define CCH  256

__device__ __forceinline__ unsigned short f2bf(float f) {
  unsigned int u = __builtin_bit_cast(unsigned int, f);
  u += 0x7FFFu + ((u >> 16) & 1u);
  return (unsigned short)(u >> 16);
}

__device__ __forceinline__ float bfu(unsigned short h) {
  unsigned int u = ((unsigned int)h) << 16;
  return __builtin_bit_cast(float, u);
}

__device__ __forceinline__ unsigned int pack2(float a, float b) {
  return (unsigned int)f2bf(a) | ((unsigned int)f2bf(b) << 16);
}

__device__ __forceinline__ void gld_lds16(const void* g, void* l) {
  __builtin_amdgcn_global_load_lds(
      (const __attribute__((address_space(1))) unsigned int*)g,
      (__attribute__((address_space(3))) unsigned int*)l, 16, 0, 0);
}

// ---------------- W conversion fp32 -> bf16, [3][256][256] ----------------
__global__ __launch_bounds__(256) void convert_w_kernel(
    const float* __restrict__ Wb, const float* __restrict__ Wc,
    const float* __restrict__ Wd, unsigned short* __restrict__ Wbf) {
  const int mat = blockIdx.y;
  const float* src = (mat == 0) ? Wb : (mat == 1) ? Wc : Wd;
  int i = (blockIdx.x * 256 + threadIdx.x) * 4;
  float4 v = *reinterpret_cast<const float4*>(src + i);
  uint2 o;
  o.x = pack2(v.x, v.y);
  o.y = pack2(v.z, v.w);
  *reinterpret_cast<uint2*>(Wbf + mat * 65536 + i) = o;
}

// ---------------- fused transpose + 3 projections (coalesced stores) ----------
__global__ __launch_bounds__(256, 2) void fused_proj_kernel(
    const float* __restrict__ x, const unsigned short* __restrict__ Wbf,
    const float* __restrict__ bb, const float* __restrict__ bc,
    const float* __restrict__ bd, unsigned short* __restrict__ Q,
    unsigned short* __restrict__ K, unsigned short* __restrict__ Vt) {
  __shared__ __align__(16) float tile[64][65];   // phase-1 scratch + bounce
  __shared__ __align__(16) char xsub[32768];
  char* bounce = (char*)tile;

  const int tid = threadIdx.x;
  const int wid = tid >> 6, lane = tid & 63;
  const int l31 = lane & 31, hi = lane >> 5;
  const int lt = blockIdx.x, n = blockIdx.y;

  // ---- phase 1: x[n][c][lt*64..] -> bf16 subtiles ----
  #pragma unroll 1
  for (int ct = 0; ct < 4; ++ct) {
    const float* xg = x + ((size_t)(n * CCH + ct * 64)) * NPIX + lt * 64;
    #pragma unroll
    for (int it = 0; it < 4; ++it) {
      int row = (tid >> 4) + it * 16;
      int col = (tid & 15) * 4;
      float4 v = *reinterpret_cast<const float4*>(xg + (size_t)row * NPIX + col);
      tile[row][col] = v.x; tile[row][col + 1] = v.y;
      tile[row][col + 2] = v.z; tile[row][col + 3] = v.w;
    }
    __syncthreads();
    #pragma unroll
    for (int it = 0; it < 2; ++it) {
      int idx = tid + it * 256;
      int l = idx >> 3;
      int ch = (idx & 7) * 8;
      int c = ct * 64 + ch;
      uint4 o;
      o.x = pack2(tile[ch + 0][l], tile[ch + 1][l]);
      o.y = pack2(tile[ch + 2][l], tile[ch + 3][l]);
      o.z = pack2(tile[ch + 4][l], tile[ch + 5][l]);
      o.w = pack2(tile[ch + 6][l], tile[ch + 7][l]);
      int addr = (l >> 5) * 16384 + (c >> 4) * 1024 + ((c >> 3) & 1) * 512 + (l & 31) * 16;
      *reinterpret_cast<uint4*>(xsub + addr) = o;
    }
    __syncthreads();
  }

  // ---- phase 2: wave = o-quarter [wid*64, wid*64+64) ----
  const int o0a = wid * 64, o0b = wid * 64 + 32;
  const size_t pixrow = (size_t)n * NPIX + lt * 64;

  #pragma unroll 1
  for (int mat = 0; mat < 3; ++mat) {
    const unsigned short* W = Wbf + mat * 65536;
    const float* bias = (mat == 0) ? bb : (mat == 1) ? bc : bd;
    f32x16 a00, a01, a10, a11;  // [oi][pix-half]
    #pragma unroll
    for (int e = 0; e < 16; ++e) { a00[e] = 0.f; a01[e] = 0.f; a10[e] = 0.f; a11[e] = 0.f; }
    #pragma unroll
    for (int c0 = 0; c0 < 16; ++c0) {
      bf16x8 x0 = *reinterpret_cast<const bf16x8*>(xsub + c0 * 1024 + lane * 16);
      bf16x8 x1 = *reinterpret_cast<const bf16x8*>(xsub + 16384 + c0 * 1024 + lane * 16);
      bf16x8 w0 = *reinterpret_cast<const bf16x8*>(W + (o0a + l31) * CCH + c0 * 16 + hi * 8);
      bf16x8 w1 = *reinterpret_cast<const bf16x8*>(W + (o0b + l31) * CCH + c0 * 16 + hi * 8);
      if (mat < 2) {
        a00 = __builtin_amdgcn_mfma_f32_32x32x16_bf16(w0, x0, a00, 0, 0, 0);
        a01 = __builtin_amdgcn_mfma_f32_32x32x16_bf16(w0, x1, a01, 0, 0, 0);
        a10 = __builtin_amdgcn_mfma_f32_32x32x16_bf16(w1, x0, a10, 0, 0, 0);
        a11 = __builtin_amdgcn_mfma_f32_32x32x16_bf16(w1, x1, a11, 0, 0, 0);
      } else {
        a00 = __builtin_amdgcn_mfma_f32_32x32x16_bf16(x0, w0, a00, 0, 0, 0);
        a01 = __builtin_amdgcn_mfma_f32_32x32x16_bf16(x1, w0, a01, 0, 0, 0);
        a10 = __builtin_amdgcn_mfma_f32_32x32x16_bf16(x0, w1, a10, 0, 0, 0);
        a11 = __builtin_amdgcn_mfma_f32_32x32x16_bf16(x1, w1, a11, 0, 0, 0);
      }
    }
    if (mat < 2) {
      unsigned short* dst = (mat == 0) ? Q : K;
      #pragma unroll 1
      for (int ph = 0; ph < 2; ++ph) {
        __syncthreads();
        const f32x16& A0 = ph ? a01 : a00;
        const f32x16& A1 = ph ? a11 : a10;
        const int swz = (l31 & 15) << 4;
        #pragma unroll
        for (int r2 = 0; r2 < 8; ++r2) {
          const int r = r2 * 2;
          const int od = (r & 3) + 8 * (r >> 2) + 4 * hi;
          const int oa = o0a + od, ob = o0b + od;
          *reinterpret_cast<unsigned int*>(bounce + ((l31 * 512 + oa * 2) ^ swz)) =
              pack2(A0[r] + bias[oa], A0[r + 1] + bias[oa + 1]);
          *reinterpret_cast<unsigned int*>(bounce + ((l31 * 512 + ob * 2) ^ swz)) =
              pack2(A1[r] + bias[ob], A1[r + 1] + bias[ob + 1]);
        }
        __syncthreads();
        const int dp = tid >> 3, obase = (tid & 7) * 32;
        const int dswz = (dp & 15) << 4;
        char* gout = (char*)(dst + (pixrow + ph * 32 + dp) * CCH + obase);
        #pragma unroll
        for (int k = 0; k < 4; ++k) {
          u32x4 v = *reinterpret_cast<const u32x4*>(
              bounce + ((dp * 512 + obase * 2 + k * 16) ^ dswz));
          *reinterpret_cast<u32x4*>(gout + k * 16) = v;
        }
      }
    } else {
      #pragma unroll 1
      for (int os = 0; os < 2; ++os) {
        __syncthreads();
        if ((wid >> 1) == os) {
          const int ola = o0a + l31 - os * 128, olb = o0b + l31 - os * 128;
          const float bva = bias[o0a + l31], bvb = bias[o0b + l31];
          const int sza = (ola & 7) << 4, szb = (olb & 7) << 4;
          #pragma unroll
          for (int r2 = 0; r2 < 8; ++r2) {
            const int r = r2 * 2;
            const int pd = (r & 3) + 8 * (r >> 2) + 4 * hi;
            *reinterpret_cast<unsigned int*>(bounce + ((ola * 128 + pd * 2) ^ sza)) =
                pack2(a00[r] + bva, a00[r + 1] + bva);
            *reinterpret_cast<unsigned int*>(bounce + ((ola * 128 + (pd + 32) * 2) ^ sza)) =
                pack2(a01[r] + bva, a01[r + 1] + bva);
            *reinterpret_cast<unsigned int*>(bounce + ((olb * 128 + pd * 2) ^ szb)) =
                pack2(a10[r] + bvb, a10[r + 1] + bvb);
            *reinterpret_cast<unsigned int*>(bounce + ((olb * 128 + (pd + 32) * 2) ^ szb)) =
                pack2(a11[r] + bvb, a11[r + 1] + bvb);
          }
        }
        __syncthreads();
        const int ol = tid >> 1, pb0 = (tid & 1) * 32;
        const int vswz = (ol & 7) << 4;
        char* gout = (char*)(Vt + ((size_t)(n * CCH + os * 128 + ol)) * NPIX + lt * 64 + pb0);
        #pragma unroll
        for (int k = 0; k < 4; ++k) {
          u32x4 v = *reinterpret_cast<const u32x4*>(
              bounce + ((ol * 128 + pb0 * 2 + k * 16) ^ vswz));
          *reinterpret_cast<u32x4*>(gout + k * 16) = v;
        }
      }
    }
  }
}

// ---------------- attention partial: one j-half per block ----------------
// 4 waves x 32 q; KVBLK=32, 64 iters; LDS 64KB: kb[2]x16KB + vb[2]x16KB.
// T15 att[2] pipeline: PV lags one iteration so softmax(t) (VALU/trans)
// interleaves with PV(t-1) (MFMA) inside one setprio region.
// Per iter t (par=t&1):
//   STAGE_K(t+1 -> kb[par^1]); STAGE_V(t -> vb[par])
//   vmcnt(8)  [drains exactly K(t)+V(t-1); K(t+1)+V(t) stay in flight]
//   barrier
//   QK(t) <- kb[par]
//   [softmax(t) VALU  ||  PV(t-1) MFMA <- vb[par^1]]  (chunk-interleaved)
//   barrier
// Buffer safety: every overwrite-issue is >=1 barrier after all waves' last
// reads of that buffer (kb[par^1]: read QK(t-1) < end-bar(t-1) < issue(t);
// vb[par]: read PV(t-2) < end-bar(t-1) < issue(t)).
__global__ __launch_bounds__(256, 2) void attn_part_kernel(
    const unsigned short* __restrict__ Q, const unsigned short* __restrict__ K,
    const unsigned short* __restrict__ Vt, unsigned short* __restrict__ Opart,
    float* __restrict__ lsumbuf) {
  __shared__ __align__(16) char smem[65536];

  const int tid = threadIdx.x;
  const int wid = tid >> 6;
  const int lane = tid & 63;
  const int l31 = lane & 31;
  const int hi = lane >> 5;
  const int lofs = lane << 4;
  const int blk = blockIdx.x;
  const int n = blk & 7;
  const int t2 = blk >> 3;
  const int half = t2 & 1;
  const int qb = t2 >> 1;
  const int q0 = qb * 128 + wid * 32;

  const unsigned short* Qg = Q + (size_t)n * NPIX * CCH;
  const char* Kg = (const char*)(K + ((size_t)n * NPIX + half * 2048) * CCH);
  const char* Vg = (const char*)(Vt + (size_t)n * CCH * NPIX + half * 2048);

  bf16x8 qf[16];
  #pragma unroll
  for (int c0 = 0; c0 < 16; ++c0)
    qf[c0] = *reinterpret_cast<const bf16x8*>(
        Qg + (size_t)(q0 + l31) * CCH + c0 * 16 + hi * 8);

  f32x16 oacc[8];
  #pragma unroll
  for (int i = 0; i < 8; ++i)
    #pragma unroll
    for (int e = 0; e < 16; ++e) oacc[i][e] = 0.f;
  float lsum = 0.f;

  // per-wave staging: wave stages chunks s = wid*4+g for both K and V
  int soffK[4];
  #pragma unroll
  for (int g = 0; g < 4; ++g)
    soffK[g] = l31 * 512 + (wid * 4 + g) * 32 + hi * 16;

  auto STAGE_K = [&](int par_, int tt) {
    #pragma unroll
    for (int g = 0; g < 4; ++g)
      gld_lds16(Kg + (size_t)soffK[g] + (size_t)tt * 16384,
                smem + par_ * 16384 + (wid * 4 + g) * 1024);
  };
  auto STAGE_V = [&](int par_, int tt) {
    #pragma unroll
    for (int g = 0; g < 4; ++g) {
      const int s = wid * 4 + g;
      const int cb = s >> 1, kk2 = s & 1;
      const int off = (cb * 32 + l31) * 8192 + (kk2 * 16 + hi * 8) * 2;
      gld_lds16(Vg + (size_t)off + (size_t)tt * 64,
                smem + 32768 + par_ * 16384 + (wid * 4 + g) * 1024);
    }
  };

  bf16x8 pa0p, pa1p;   // P(t-1) fragments (loop-carried)

  // ---------- prologue + peeled iter 0 (no PV) ----------
  STAGE_K(0, 0);
  STAGE_K(1, 1);
  STAGE_V(0, 0);
  __builtin_amdgcn_sched_barrier(0);
  asm volatile("s_waitcnt vmcnt(8)" ::: "memory");   // K(0) done
  __builtin_amdgcn_s_barrier();
  __builtin_amdgcn_sched_barrier(0);

  {
    const char* kb = smem;   // kb[0]
    f32x16 S;
    #pragma unroll
    for (int e = 0; e < 16; ++e) S[e] = 0.f;
    __builtin_amdgcn_s_setprio(1);
    #pragma unroll
    for (int c0 = 0; c0 < 16; ++c0) {
      bf16x8 kf = *reinterpret_cast<const bf16x8*>(kb + c0 * 1024 + lofs);
      S = __builtin_amdgcn_mfma_f32_32x32x16_bf16(kf, qf[c0], S, 0, 0, 0);
    }
    __builtin_amdgcn_s_setprio(0);

    float rsum = 0.f;
    unsigned int pw[8];
    #pragma unroll
    for (int i = 0; i < 8; ++i) {
      float p0 = exp2f(fmaf(S[2 * i],     1.44269504f, -101.0f));
      float p1 = exp2f(fmaf(S[2 * i + 1], 1.44269504f, -101.0f));
      rsum += p0 + p1;
      unsigned int r;
      asm("v_cvt_pk_bf16_f32 %0, %1, %2" : "=v"(r) : "v"(p0), "v"(p1));
      pw[i] = r;
    }
    lsum += rsum;
    unsigned int s0a = pw[0], s0b = pw[2];
    unsigned int s1a = pw[1], s1b = pw[3];
    unsigned int s2a = pw[4], s2b = pw[6];
    unsigned int s3a = pw[5], s3b = pw[7];
    asm volatile("v_permlane32_swap_b32 %0, %1" : "+v"(s0a), "+v"(s0b));
    asm volatile("v_permlane32_swap_b32 %0, %1" : "+v"(s1a), "+v"(s1b));
    asm volatile("v_permlane32_swap_b32 %0, %1" : "+v"(s2a), "+v"(s2b));
    asm volatile("v_permlane32_swap_b32 %0, %1" : "+v"(s3a), "+v"(s3b));
    u32x4 f0, f1;
    f0[0] = s0a; f0[1] = s1a; f0[2] = s0b; f0[3] = s1b;
    f1[0] = s2a; f1[1] = s3a; f1[2] = s2b; f1[3] = s3b;
    pa0p = __builtin_bit_cast(bf16x8, f0);
    pa1p = __builtin_bit_cast(bf16x8, f1);
  }
  __builtin_amdgcn_s_barrier();   // end of iter 0

  // ---------- steady loop t = 1..63 ----------
  #pragma unroll 1
  for (int t = 1; t < 64; ++t) {
    const int par = t & 1;
    const char* kb = smem + par * 16384;
    const char* vbp = smem + 32768 + (par ^ 1) * 16384;   // V(t-1)

    STAGE_K(par ^ 1, (t + 1) & 63);
    STAGE_V(par, t);
    __builtin_amdgcn_sched_barrier(0);
    asm volatile("s_waitcnt vmcnt(8)" ::: "memory");   // K(t), V(t-1) done
    __builtin_amdgcn_s_barrier();
    __builtin_amdgcn_sched_barrier(0);

    // ---- QK^T(t) ----
    f32x16 S;
    #pragma unroll
    for (int e = 0; e < 16; ++e) S[e] = 0.f;
    __builtin_amdgcn_s_setprio(1);
    #pragma unroll
    for (int c0 = 0; c0 < 16; ++c0) {
      bf16x8 kf = *reinterpret_cast<const bf16x8*>(kb + c0 * 1024 + lofs);
      S = __builtin_amdgcn_mfma_f32_32x32x16_bf16(kf, qf[c0], S, 0, 0, 0);
    }

    // ---- softmax(t) interleaved with PV(t-1) ----
    float rsum = 0.f;
    unsigned int pw[8];
    #pragma unroll
    for (int i = 0; i < 8; ++i) {
      float p0 = exp2f(fmaf(S[2 * i],     1.44269504f, -101.0f));
      float p1 = exp2f(fmaf(S[2 * i + 1], 1.44269504f, -101.0f));
      rsum += p0 + p1;
      unsigned int r;
      asm("v_cvt_pk_bf16_f32 %0, %1, %2" : "=v"(r) : "v"(p0), "v"(p1));
      pw[i] = r;
      bf16x8 v0 = *reinterpret_cast<const bf16x8*>(vbp + (i * 2 + 0) * 1024 + lofs);
      oacc[i] = __builtin_amdgcn_mfma_f32_32x32x16_bf16(pa0p, v0, oacc[i], 0, 0, 0);
      bf16x8 v1 = *reinterpret_cast<const bf16x8*>(vbp + (i * 2 + 1) * 1024 + lofs);
      oacc[i] = __builtin_amdgcn_mfma_f32_32x32x16_bf16(pa1p, v1, oacc[i], 0, 0, 0);
    }
    __builtin_amdgcn_s_setprio(0);
    lsum += rsum;

    // ---- pack P(t) for next iter's PV ----
    unsigned int s0a = pw[0], s0b = pw[2];
    unsigned int s1a = pw[1], s1b = pw[3];
    unsigned int s2a = pw[4], s2b = pw[6];
    unsigned int s3a = pw[5], s3b = pw[7];
    asm volatile("v_permlane32_swap_b32 %0, %1" : "+v"(s0a), "+v"(s0b));
    asm volatile("v_permlane32_swap_b32 %0, %1" : "+v"(s1a), "+v"(s1b));
    asm volatile("v_permlane32_swap_b32 %0, %1" : "+v"(s2a), "+v"(s2b));
    asm volatile("v_permlane32_swap_b32 %0, %1" : "+v"(s3a), "+v"(s3b));
    u32x4 f0, f1;
    f0[0] = s0a; f0[1] = s1a; f0[2] = s0b; f0[3] = s1b;
    f1[0] = s2a; f1[1] = s3a; f1[2] = s2b; f1[3] = s3b;
    pa0p = __builtin_bit_cast(bf16x8, f0);
    pa1p = __builtin_bit_cast(bf16x8, f1);

    __builtin_amdgcn_s_barrier();   // end of iter t
  }

  // ---------- epilogue: PV(63) ----------
  asm volatile("s_waitcnt vmcnt(0)" ::: "memory");   // V(63) (+junk K restage)
  __builtin_amdgcn_s_barrier();
  {
    const char* vbp = smem + 32768 + 16384;   // vb[1] = V(63)
    __builtin_amdgcn_s_setprio(1);
    #pragma unroll
    for (int cb = 0; cb < 8; ++cb) {
      bf16x8 v0 = *reinterpret_cast<const bf16x8*>(vbp + (cb * 2 + 0) * 1024 + lofs);
      oacc[cb] = __builtin_amdgcn_mfma_f32_32x32x16_bf16(pa0p, v0, oacc[cb], 0, 0, 0);
      bf16x8 v1 = *reinterpret_cast<const bf16x8*>(vbp + (cb * 2 + 1) * 1024 + lofs);
      oacc[cb] = __builtin_amdgcn_mfma_f32_32x32x16_bf16(pa1p, v1, oacc[cb], 0, 0, 0);
    }
    __builtin_amdgcn_s_setprio(0);
  }

  lsum += __shfl_xor(lsum, 32);
  char* slab = (char*)Opart + (size_t)blk * 65536;
  #pragma unroll
  for (int cb = 0; cb < 8; ++cb) {
    u32x4 u0, u1;
    u0[0] = pack2(oacc[cb][0],  oacc[cb][1]);
    u0[1] = pack2(oacc[cb][2],  oacc[cb][3]);
    u0[2] = pack2(oacc[cb][4],  oacc[cb][5]);
    u0[3] = pack2(oacc[cb][6],  oacc[cb][7]);
    u1[0] = pack2(oacc[cb][8],  oacc[cb][9]);
    u1[1] = pack2(oacc[cb][10], oacc[cb][11]);
    u1[2] = pack2(oacc[cb][12], oacc[cb][13]);
    u1[3] = pack2(oacc[cb][14], oacc[cb][15]);
    *reinterpret_cast<u32x4*>(slab + (cb * 2 + 0) * 4096 + tid * 16) = u0;
    *reinterpret_cast<u32x4*>(slab + (cb * 2 + 1) * 4096 + tid * 16) = u1;
  }
  if (hi == 0) lsumbuf[blk * 128 + wid * 32 + l31] = lsum;
}

// ---------------- merge halves + normalize + residual + transpose ----------------
// grid 256 = (n, qb); 512 threads (8 waves -> better latency hiding).
// Thread (pr8 = tid>>6): qsub = pr8&3, cb-half = pr8>>2.
__global__ __launch_bounds__(512) void merge_kernel(
    const unsigned short* __restrict__ Opart, const float* __restrict__ lsumbuf,
    const float* __restrict__ x, const float* __restrict__ alpha_p,
    float* __restrict__ out) {
  __shared__ float T[32768];   // [c 0..255][q' 0..127], elem = c*128 + (q'^(c&28))
  __shared__ float Lq[128];

  const int tid = threadIdx.x;
  const int pr8 = tid >> 6;
  const int lane = tid & 63;
  const int l31 = lane & 31;
  const int hi = lane >> 5;
  const int qsub = pr8 & 3;
  const int cbh = pr8 >> 2;
  const int atid = qsub * 64 + lane;    // matching attn-slab thread index
  const int m = blockIdx.x;
  const int n = m & 7;
  const int qb = m >> 3;
  const int blkA = n + 8 * (0 + 2 * qb);
  const int blkB = n + 8 * (1 + 2 * qb);

  if (tid < 128)
    Lq[tid] = alpha_p[0] / (lsumbuf[blkA * 128 + tid] + lsumbuf[blkB * 128 + tid]);
  __syncthreads();

  const char* sa = (const char*)Opart + (size_t)blkA * 65536;
  const char* sb = (const char*)Opart + (size_t)blkB * 65536;

  #pragma unroll
  for (int cbi = 0; cbi < 4; ++cbi) {
    const int cb = cbh * 4 + cbi;
    const int c = cb * 32 + l31;
    const int swz = c & 28;
    #pragma unroll
    for (int h = 0; h < 2; ++h) {
      u32x4 a = *reinterpret_cast<const u32x4*>(sa + (cb * 2 + h) * 4096 + atid * 16);
      u32x4 b = *reinterpret_cast<const u32x4*>(sb + (cb * 2 + h) * 4096 + atid * 16);
      #pragma unroll
      for (int w = 0; w < 4; ++w) {
        const int r = h * 8 + w * 2;
        float v0 = bfu((unsigned short)(a[w] & 0xFFFF)) + bfu((unsigned short)(b[w] & 0xFFFF));
        float v1 = bfu((unsigned short)(a[w] >> 16)) + bfu((unsigned short)(b[w] >> 16));
        const int q0l = qsub * 32 + ((r) & 3) + 8 * ((r) >> 2) + 4 * hi;
        const int q1l = q0l + 1;
        T[c * 128 + (q0l ^ swz)] = v0 * Lq[q0l];
        T[c * 128 + (q1l ^ swz)] = v1 * Lq[q1l];
      }
    }
  }
  __syncthreads();

  // write out: 16 sweeps, 16 c-rows per sweep, float4 per thread
  const int l0 = (tid & 31) * 4;
  #pragma unroll 4
  for (int sw = 0; sw < 16; ++sw) {
    const int c = (tid >> 5) + sw * 16;
    const float* src = &T[c * 128 + (l0 ^ (c & 28))];
    float4 v = *reinterpret_cast<const float4*>(src);
    const size_t g = ((size_t)n * CCH + c) * NPIX + qb * 128 + l0;
    float4 xi = *reinterpret_cast<const float4*>(x + g);
    float4 o;
    o.x = v.x + xi.x; o.y = v.y + xi.y; o.z = v.z + xi.z; o.w = v.w + xi.w;
    *reinterpret_cast<float4*>(out + g) = o;
  }
}

extern "C" void kernel_launch(void* const* d_in, const int* in_sizes, int n_in,
                              void* d_out, int out_size, void* d_ws, size_t ws_size,
                              hipStream_t stream) {
  const float* x  = (const float*)d_in[0];
  const float* Wb = (const float*)d_in[1];
  const float* bb = (const float*)d_in[2];
  const float* Wc = (const float*)d_in[3];
  const float* bc = (const float*)d_in[4];
  const float* Wd = (const float*)d_in[5];
  const float* bd = (const float*)d_in[6];
  const float* alpha = (const float*)d_in[7];
  float* out = (float*)d_out;
  char* ws = (char*)d_ws;

  unsigned short* Wbf   = (unsigned short*)(ws);                //    393,216 B
  unsigned short* Q     = (unsigned short*)(ws + 393216);       // 16,777,216 B
  unsigned short* K     = (unsigned short*)(ws + 17170432);     // 16,777,216 B
  unsigned short* Vt    = (unsigned short*)(ws + 33947648);     // 16,777,216 B
  unsigned short* Opart = (unsigned short*)(ws + 50724864);     // 33,554,432 B
  float*          lsumb = (float*)(ws + 84279296);              //    262,144 B

  convert_w_kernel<<<dim3(64, 3), 256, 0, stream>>>(Wb, Wc, Wd, Wbf);
  fused_proj_kernel<<<dim3(64, 8), 256, 0, stream>>>(x, Wbf, bb, bc, bd, Q, K, Vt);
  attn_part_kernel<<<dim3(512), 256, 0, stream>>>(Q, K, Vt, Opart, lsumb);
  merge_kernel<<<dim3(256), 512, 0, stream>>>(Opart, lsumb, x, alpha, out);
}

// Round 3
// 216.617 us; speedup vs baseline: 1.0103x; 1.0054x over previous
//
#include <hip/hip_runtime.h>

using bf16x8 = __attribute__((ext_vector_type(8))) short;
using f32x4  = __attribute__((ext_vector_type(4))) float;
using f32x16 = __attribute__((ext_vector_type(16))) float;
using u32x4  = __attribute__((ext_vector_type(4))) unsigned int;

#define NPIX 4096
#define CCH  256

__device__ __forceinline__ unsigned short f2bf(float f) {
  unsigned int u = __builtin_bit_cast(unsigned int, f);
  u += 0x7FFFu + ((u >> 16) & 1u);
  return (unsigned short)(u >> 16);
}

__device__ __forceinline__ float bfu(unsigned short h) {
  unsigned int u = ((unsigned int)h) << 16;
  return __builtin_bit_cast(float, u);
}

__device__ __forceinline__ unsigned int pack2(float a, float b) {
  return (unsigned int)f2bf(a) | ((unsigned int)f2bf(b) << 16);
}

__device__ __forceinline__ void gld_lds16(const void* g, void* l) {
  __builtin_amdgcn_global_load_lds(
      (const __attribute__((address_space(1))) unsigned int*)g,
      (__attribute__((address_space(3))) unsigned int*)l, 16, 0, 0);
}

// ---------------- W conversion fp32 -> bf16, [3][256][256] ----------------
__global__ __launch_bounds__(256) void convert_w_kernel(
    const float* __restrict__ Wb, const float* __restrict__ Wc,
    const float* __restrict__ Wd, unsigned short* __restrict__ Wbf) {
  const int mat = blockIdx.y;
  const float* src = (mat == 0) ? Wb : (mat == 1) ? Wc : Wd;
  int i = (blockIdx.x * 256 + threadIdx.x) * 4;
  float4 v = *reinterpret_cast<const float4*>(src + i);
  uint2 o;
  o.x = pack2(v.x, v.y);
  o.y = pack2(v.z, v.w);
  *reinterpret_cast<uint2*>(Wbf + mat * 65536 + i) = o;
}

// ---------------- fused transpose + 3 projections (coalesced stores) ----------
__global__ __launch_bounds__(256, 2) void fused_proj_kernel(
    const float* __restrict__ x, const unsigned short* __restrict__ Wbf,
    const float* __restrict__ bb, const float* __restrict__ bc,
    const float* __restrict__ bd, unsigned short* __restrict__ Q,
    unsigned short* __restrict__ K, unsigned short* __restrict__ Vt) {
  __shared__ __align__(16) float tile[64][68];   // 68: rows 16B-aligned -> b128 LDS writes
  __shared__ __align__(16) char xsub[32768];
  char* bounce = (char*)tile;

  const int tid = threadIdx.x;
  const int wid = tid >> 6, lane = tid & 63;
  const int l31 = lane & 31, hi = lane >> 5;
  const int lt = blockIdx.x, n = blockIdx.y;

  // ---- phase 1: x[n][c][lt*64..] -> bf16 subtiles ----
  #pragma unroll 1
  for (int ct = 0; ct < 4; ++ct) {
    const float* xg = x + ((size_t)(n * CCH + ct * 64)) * NPIX + lt * 64;
    #pragma unroll
    for (int it = 0; it < 4; ++it) {
      int row = (tid >> 4) + it * 16;
      int col = (tid & 15) * 4;
      float4 v = *reinterpret_cast<const float4*>(xg + (size_t)row * NPIX + col);
      *reinterpret_cast<float4*>(&tile[row][col]) = v;   // b128 LDS write (aligned)
    }
    __syncthreads();
    #pragma unroll
    for (int it = 0; it < 2; ++it) {
      int idx = tid + it * 256;
      int l = idx >> 3;
      int ch = (idx & 7) * 8;
      int c = ct * 64 + ch;
      uint4 o;
      o.x = pack2(tile[ch + 0][l], tile[ch + 1][l]);
      o.y = pack2(tile[ch + 2][l], tile[ch + 3][l]);
      o.z = pack2(tile[ch + 4][l], tile[ch + 5][l]);
      o.w = pack2(tile[ch + 6][l], tile[ch + 7][l]);
      int addr = (l >> 5) * 16384 + (c >> 4) * 1024 + ((c >> 3) & 1) * 512 + (l & 31) * 16;
      *reinterpret_cast<uint4*>(xsub + addr) = o;
    }
    __syncthreads();
  }

  // ---- phase 2: wave = o-quarter [wid*64, wid*64+64) ----
  const int o0a = wid * 64, o0b = wid * 64 + 32;
  const size_t pixrow = (size_t)n * NPIX + lt * 64;

  #pragma unroll 1
  for (int mat = 0; mat < 3; ++mat) {
    const unsigned short* W = Wbf + mat * 65536;
    const float* bias = (mat == 0) ? bb : (mat == 1) ? bc : bd;
    f32x16 a00, a01, a10, a11;  // [oi][pix-half]
    #pragma unroll
    for (int e = 0; e < 16; ++e) { a00[e] = 0.f; a01[e] = 0.f; a10[e] = 0.f; a11[e] = 0.f; }
    #pragma unroll
    for (int c0 = 0; c0 < 16; ++c0) {
      bf16x8 x0 = *reinterpret_cast<const bf16x8*>(xsub + c0 * 1024 + lane * 16);
      bf16x8 x1 = *reinterpret_cast<const bf16x8*>(xsub + 16384 + c0 * 1024 + lane * 16);
      bf16x8 w0 = *reinterpret_cast<const bf16x8*>(W + (o0a + l31) * CCH + c0 * 16 + hi * 8);
      bf16x8 w1 = *reinterpret_cast<const bf16x8*>(W + (o0b + l31) * CCH + c0 * 16 + hi * 8);
      if (mat < 2) {
        a00 = __builtin_amdgcn_mfma_f32_32x32x16_bf16(w0, x0, a00, 0, 0, 0);
        a01 = __builtin_amdgcn_mfma_f32_32x32x16_bf16(w0, x1, a01, 0, 0, 0);
        a10 = __builtin_amdgcn_mfma_f32_32x32x16_bf16(w1, x0, a10, 0, 0, 0);
        a11 = __builtin_amdgcn_mfma_f32_32x32x16_bf16(w1, x1, a11, 0, 0, 0);
      } else {
        a00 = __builtin_amdgcn_mfma_f32_32x32x16_bf16(x0, w0, a00, 0, 0, 0);
        a01 = __builtin_amdgcn_mfma_f32_32x32x16_bf16(x1, w0, a01, 0, 0, 0);
        a10 = __builtin_amdgcn_mfma_f32_32x32x16_bf16(x0, w1, a10, 0, 0, 0);
        a11 = __builtin_amdgcn_mfma_f32_32x32x16_bf16(x1, w1, a11, 0, 0, 0);
      }
    }
    if (mat < 2) {
      unsigned short* dst = (mat == 0) ? Q : K;
      #pragma unroll 1
      for (int ph = 0; ph < 2; ++ph) {
        __syncthreads();
        const f32x16& A0 = ph ? a01 : a00;
        const f32x16& A1 = ph ? a11 : a10;
        const int swz = (l31 & 15) << 4;
        #pragma unroll
        for (int r2 = 0; r2 < 8; ++r2) {
          const int r = r2 * 2;
          const int od = (r & 3) + 8 * (r >> 2) + 4 * hi;
          const int oa = o0a + od, ob = o0b + od;
          *reinterpret_cast<unsigned int*>(bounce + ((l31 * 512 + oa * 2) ^ swz)) =
              pack2(A0[r] + bias[oa], A0[r + 1] + bias[oa + 1]);
          *reinterpret_cast<unsigned int*>(bounce + ((l31 * 512 + ob * 2) ^ swz)) =
              pack2(A1[r] + bias[ob], A1[r + 1] + bias[ob + 1]);
        }
        __syncthreads();
        const int dp = tid >> 3, obase = (tid & 7) * 32;
        const int dswz = (dp & 15) << 4;
        char* gout = (char*)(dst + (pixrow + ph * 32 + dp) * CCH + obase);
        #pragma unroll
        for (int k = 0; k < 4; ++k) {
          u32x4 v = *reinterpret_cast<const u32x4*>(
              bounce + ((dp * 512 + obase * 2 + k * 16) ^ dswz));
          *reinterpret_cast<u32x4*>(gout + k * 16) = v;
        }
      }
    } else {
      #pragma unroll 1
      for (int os = 0; os < 2; ++os) {
        __syncthreads();
        if ((wid >> 1) == os) {
          const int ola = o0a + l31 - os * 128, olb = o0b + l31 - os * 128;
          const float bva = bias[o0a + l31], bvb = bias[o0b + l31];
          const int sza = (ola & 7) << 4, szb = (olb & 7) << 4;
          #pragma unroll
          for (int r2 = 0; r2 < 8; ++r2) {
            const int r = r2 * 2;
            const int pd = (r & 3) + 8 * (r >> 2) + 4 * hi;
            *reinterpret_cast<unsigned int*>(bounce + ((ola * 128 + pd * 2) ^ sza)) =
                pack2(a00[r] + bva, a00[r + 1] + bva);
            *reinterpret_cast<unsigned int*>(bounce + ((ola * 128 + (pd + 32) * 2) ^ sza)) =
                pack2(a01[r] + bva, a01[r + 1] + bva);
            *reinterpret_cast<unsigned int*>(bounce + ((olb * 128 + pd * 2) ^ szb)) =
                pack2(a10[r] + bvb, a10[r + 1] + bvb);
            *reinterpret_cast<unsigned int*>(bounce + ((olb * 128 + (pd + 32) * 2) ^ szb)) =
                pack2(a11[r] + bvb, a11[r + 1] + bvb);
          }
        }
        __syncthreads();
        const int ol = tid >> 1, pb0 = (tid & 1) * 32;
        const int vswz = (ol & 7) << 4;
        char* gout = (char*)(Vt + ((size_t)(n * CCH + os * 128 + ol)) * NPIX + lt * 64 + pb0);
        #pragma unroll
        for (int k = 0; k < 4; ++k) {
          u32x4 v = *reinterpret_cast<const u32x4*>(
              bounce + ((ol * 128 + pb0 * 2 + k * 16) ^ vswz));
          *reinterpret_cast<u32x4*>(gout + k * 16) = v;
        }
      }
    }
  }
}

// ---------------- attention partial: one j-half per block (R0 schedule) ----
// 4 waves x 32 q; KVBLK=32, 64 iters, dbuf 2x32KB -> 2 blocks/CU.
// Fixed-offset softmax P = exp2(S*log2e - 101); cvt_pk + permlane32_swap.
// STAGE for t+1 issued after QK^T's reads (round-8 proven position).
// PV runs ks-major: all pa0*v0 MFMAs hit distinct oacc[cb] before the pa1*v1
// sweep -> no back-to-back same-accumulator MFMA pairs (dep-latency relief);
// per-accumulator summation order unchanged (bit-identical numerics).
__global__ __launch_bounds__(256, 2) void attn_part_kernel(
    const unsigned short* __restrict__ Q, const unsigned short* __restrict__ K,
    const unsigned short* __restrict__ Vt, unsigned short* __restrict__ Opart,
    float* __restrict__ lsumbuf) {
  __shared__ __align__(16) char smem[65536];

  const int tid = threadIdx.x;
  const int wid = tid >> 6;
  const int lane = tid & 63;
  const int l31 = lane & 31;
  const int hi = lane >> 5;
  const int lofs = lane << 4;
  const int blk = blockIdx.x;
  const int n = blk & 7;
  const int t2 = blk >> 3;
  const int half = t2 & 1;
  const int qb = t2 >> 1;
  const int q0 = qb * 128 + wid * 32;

  const unsigned short* Qg = Q + (size_t)n * NPIX * CCH;
  const char* Kg = (const char*)(K + ((size_t)n * NPIX + half * 2048) * CCH);
  const char* Vg = (const char*)(Vt + (size_t)n * CCH * NPIX + half * 2048);

  bf16x8 qf[16];
  #pragma unroll
  for (int c0 = 0; c0 < 16; ++c0)
    qf[c0] = *reinterpret_cast<const bf16x8*>(
        Qg + (size_t)(q0 + l31) * CCH + c0 * 16 + hi * 8);

  f32x16 oacc[8];
  #pragma unroll
  for (int i = 0; i < 8; ++i)
    #pragma unroll
    for (int e = 0; e < 16; ++e) oacc[i][e] = 0.f;
  float lsum = 0.f;

  const bool isK = wid < 2;
  const char* splane = isK ? Kg : Vg;
  const int sinc = isK ? 32 * 512 : 64;
  int soff[8];
  #pragma unroll
  for (int g = 0; g < 8; ++g) {
    int s = ((wid & 1) << 3) + g;
    if (isK) {
      soff[g] = l31 * 512 + s * 32 + hi * 16;
    } else {
      int cb = s >> 1, kk2 = s & 1;
      soff[g] = (cb * 32 + l31) * 8192 + (kk2 * 16 + hi * 8) * 2;
    }
  }

  auto STAGE = [&](int par, int adv) {
    #pragma unroll
    for (int g = 0; g < 8; ++g)
      gld_lds16(splane + (size_t)soff[g] + (size_t)adv,
                smem + par * 32768 + (((wid << 3) + g) << 10));
  };

  STAGE(0, 0);
  __syncthreads();

  #pragma unroll 1
  for (int t = 0; t < 64; ++t) {
    const int par = t & 1;
    const char* kb = smem + par * 32768;
    const char* vb = kb + 16384;

    f32x16 S;
    #pragma unroll
    for (int e = 0; e < 16; ++e) S[e] = 0.f;
    __builtin_amdgcn_s_setprio(1);
    #pragma unroll
    for (int c0 = 0; c0 < 16; ++c0) {
      bf16x8 kf = *reinterpret_cast<const bf16x8*>(kb + c0 * 1024 + lofs);
      S = __builtin_amdgcn_mfma_f32_32x32x16_bf16(kf, qf[c0], S, 0, 0, 0);
    }
    __builtin_amdgcn_s_setprio(0);

    // prefetch of next tile issued while softmax runs
    if (t < 63) STAGE(par ^ 1, (t + 1) * sinc);

    // ---- fixed-offset softmax: P = exp2(S*log2e - 101), pack via cvt_pk ----
    float rsum = 0.f;
    unsigned int pw[8];
    #pragma unroll
    for (int i = 0; i < 8; ++i) {
      float p0 = exp2f(fmaf(S[2 * i],     1.44269504f, -101.0f));
      float p1 = exp2f(fmaf(S[2 * i + 1], 1.44269504f, -101.0f));
      rsum += p0 + p1;
      unsigned int r;
      asm("v_cvt_pk_bf16_f32 %0, %1, %2" : "=v"(r) : "v"(p0), "v"(p1));
      pw[i] = r;
    }
    lsum += rsum;

    // ---- P re-layout via permlane32_swap ----
    unsigned int s0a = pw[0], s0b = pw[2];
    unsigned int s1a = pw[1], s1b = pw[3];
    unsigned int s2a = pw[4], s2b = pw[6];
    unsigned int s3a = pw[5], s3b = pw[7];
    asm volatile("v_permlane32_swap_b32 %0, %1" : "+v"(s0a), "+v"(s0b));
    asm volatile("v_permlane32_swap_b32 %0, %1" : "+v"(s1a), "+v"(s1b));
    asm volatile("v_permlane32_swap_b32 %0, %1" : "+v"(s2a), "+v"(s2b));
    asm volatile("v_permlane32_swap_b32 %0, %1" : "+v"(s3a), "+v"(s3b));
    u32x4 f0, f1;
    f0[0] = s0a; f0[1] = s1a; f0[2] = s0b; f0[3] = s1b;
    f1[0] = s2a; f1[1] = s3a; f1[2] = s2b; f1[3] = s3b;
    bf16x8 pa0 = __builtin_bit_cast(bf16x8, f0);
    bf16x8 pa1 = __builtin_bit_cast(bf16x8, f1);

    __builtin_amdgcn_s_setprio(1);
    #pragma unroll
    for (int cb = 0; cb < 8; ++cb) {
      bf16x8 v0 = *reinterpret_cast<const bf16x8*>(vb + (cb * 2 + 0) * 1024 + lofs);
      oacc[cb] = __builtin_amdgcn_mfma_f32_32x32x16_bf16(pa0, v0, oacc[cb], 0, 0, 0);
    }
    #pragma unroll
    for (int cb = 0; cb < 8; ++cb) {
      bf16x8 v1 = *reinterpret_cast<const bf16x8*>(vb + (cb * 2 + 1) * 1024 + lofs);
      oacc[cb] = __builtin_amdgcn_mfma_f32_32x32x16_bf16(pa1, v1, oacc[cb], 0, 0, 0);
    }
    __builtin_amdgcn_s_setprio(0);

    __syncthreads();
  }

  lsum += __shfl_xor(lsum, 32);
  char* slab = (char*)Opart + (size_t)blk * 65536;
  #pragma unroll
  for (int cb = 0; cb < 8; ++cb) {
    u32x4 u0, u1;
    u0[0] = pack2(oacc[cb][0],  oacc[cb][1]);
    u0[1] = pack2(oacc[cb][2],  oacc[cb][3]);
    u0[2] = pack2(oacc[cb][4],  oacc[cb][5]);
    u0[3] = pack2(oacc[cb][6],  oacc[cb][7]);
    u1[0] = pack2(oacc[cb][8],  oacc[cb][9]);
    u1[1] = pack2(oacc[cb][10], oacc[cb][11]);
    u1[2] = pack2(oacc[cb][12], oacc[cb][13]);
    u1[3] = pack2(oacc[cb][14], oacc[cb][15]);
    *reinterpret_cast<u32x4*>(slab + (cb * 2 + 0) * 4096 + tid * 16) = u0;
    *reinterpret_cast<u32x4*>(slab + (cb * 2 + 1) * 4096 + tid * 16) = u1;
  }
  if (hi == 0) lsumbuf[blk * 128 + wid * 32 + l31] = lsum;
}

// ---------------- merge halves + normalize + residual + transpose ----------------
// grid 256 = (n, qb); 512 threads (8 waves -> better latency hiding).
// Thread (pr8 = tid>>6): qsub = pr8&3, cb-half = pr8>>2.
__global__ __launch_bounds__(512) void merge_kernel(
    const unsigned short* __restrict__ Opart, const float* __restrict__ lsumbuf,
    const float* __restrict__ x, const float* __restrict__ alpha_p,
    float* __restrict__ out) {
  __shared__ float T[32768];   // [c 0..255][q' 0..127], elem = c*128 + (q'^(c&28))
  __shared__ float Lq[128];

  const int tid = threadIdx.x;
  const int pr8 = tid >> 6;
  const int lane = tid & 63;
  const int l31 = lane & 31;
  const int hi = lane >> 5;
  const int qsub = pr8 & 3;
  const int cbh = pr8 >> 2;
  const int atid = qsub * 64 + lane;    // matching attn-slab thread index
  const int m = blockIdx.x;
  const int n = m & 7;
  const int qb = m >> 3;
  const int blkA = n + 8 * (0 + 2 * qb);
  const int blkB = n + 8 * (1 + 2 * qb);

  if (tid < 128)
    Lq[tid] = alpha_p[0] / (lsumbuf[blkA * 128 + tid] + lsumbuf[blkB * 128 + tid]);
  __syncthreads();

  const char* sa = (const char*)Opart + (size_t)blkA * 65536;
  const char* sb = (const char*)Opart + (size_t)blkB * 65536;

  #pragma unroll
  for (int cbi = 0; cbi < 4; ++cbi) {
    const int cb = cbh * 4 + cbi;
    const int c = cb * 32 + l31;
    const int swz = c & 28;
    #pragma unroll
    for (int h = 0; h < 2; ++h) {
      u32x4 a = *reinterpret_cast<const u32x4*>(sa + (cb * 2 + h) * 4096 + atid * 16);
      u32x4 b = *reinterpret_cast<const u32x4*>(sb + (cb * 2 + h) * 4096 + atid * 16);
      #pragma unroll
      for (int w = 0; w < 4; ++w) {
        const int r = h * 8 + w * 2;
        float v0 = bfu((unsigned short)(a[w] & 0xFFFF)) + bfu((unsigned short)(b[w] & 0xFFFF));
        float v1 = bfu((unsigned short)(a[w] >> 16)) + bfu((unsigned short)(b[w] >> 16));
        const int q0l = qsub * 32 + ((r) & 3) + 8 * ((r) >> 2) + 4 * hi;
        const int q1l = q0l + 1;
        T[c * 128 + (q0l ^ swz)] = v0 * Lq[q0l];
        T[c * 128 + (q1l ^ swz)] = v1 * Lq[q1l];
      }
    }
  }
  __syncthreads();

  // write out: 16 sweeps, 16 c-rows per sweep, float4 per thread
  const int l0 = (tid & 31) * 4;
  #pragma unroll 4
  for (int sw = 0; sw < 16; ++sw) {
    const int c = (tid >> 5) + sw * 16;
    const float* src = &T[c * 128 + (l0 ^ (c & 28))];
    float4 v = *reinterpret_cast<const float4*>(src);
    const size_t g = ((size_t)n * CCH + c) * NPIX + qb * 128 + l0;
    float4 xi = *reinterpret_cast<const float4*>(x + g);
    float4 o;
    o.x = v.x + xi.x; o.y = v.y + xi.y; o.z = v.z + xi.z; o.w = v.w + xi.w;
    *reinterpret_cast<float4*>(out + g) = o;
  }
}

extern "C" void kernel_launch(void* const* d_in, const int* in_sizes, int n_in,
                              void* d_out, int out_size, void* d_ws, size_t ws_size,
                              hipStream_t stream) {
  const float* x  = (const float*)d_in[0];
  const float* Wb = (const float*)d_in[1];
  const float* bb = (const float*)d_in[2];
  const float* Wc = (const float*)d_in[3];
  const float* bc = (const float*)d_in[4];
  const float* Wd = (const float*)d_in[5];
  const float* bd = (const float*)d_in[6];
  const float* alpha = (const float*)d_in[7];
  float* out = (float*)d_out;
  char* ws = (char*)d_ws;

  unsigned short* Wbf   = (unsigned short*)(ws);                //    393,216 B
  unsigned short* Q     = (unsigned short*)(ws + 393216);       // 16,777,216 B
  unsigned short* K     = (unsigned short*)(ws + 17170432);     // 16,777,216 B
  unsigned short* Vt    = (unsigned short*)(ws + 33947648);     // 16,777,216 B
  unsigned short* Opart = (unsigned short*)(ws + 50724864);     // 33,554,432 B
  float*          lsumb = (float*)(ws + 84279296);              //    262,144 B

  convert_w_kernel<<<dim3(64, 3), 256, 0, stream>>>(Wb, Wc, Wd, Wbf);
  fused_proj_kernel<<<dim3(64, 8), 256, 0, stream>>>(x, Wbf, bb, bc, bd, Q, K, Vt);
  attn_part_kernel<<<dim3(512), 256, 0, stream>>>(Q, K, Vt, Opart, lsumb);
  merge_kernel<<<dim3(256), 512, 0, stream>>>(Opart, lsumb, x, alpha, out);
}

// Round 4
// 214.916 us; speedup vs baseline: 1.0183x; 1.0079x over previous
//
#include <hip/hip_runtime.h>

using bf16x8 = __attribute__((ext_vector_type(8))) short;
using f32x4  = __attribute__((ext_vector_type(4))) float;
using f32x16 = __attribute__((ext_vector_type(16))) float;
using u32x4  = __attribute__((ext_vector_type(4))) unsigned int;

#define NPIX 4096
#define CCH  256

__device__ __forceinline__ unsigned short f2bf(float f) {
  unsigned int u = __builtin_bit_cast(unsigned int, f);
  u += 0x7FFFu + ((u >> 16) & 1u);
  return (unsigned short)(u >> 16);
}

__device__ __forceinline__ float bfu(unsigned short h) {
  unsigned int u = ((unsigned int)h) << 16;
  return __builtin_bit_cast(float, u);
}

__device__ __forceinline__ unsigned int pack2(float a, float b) {
  return (unsigned int)f2bf(a) | ((unsigned int)f2bf(b) << 16);
}

__device__ __forceinline__ void gld_lds16(const void* g, void* l) {
  __builtin_amdgcn_global_load_lds(
      (const __attribute__((address_space(1))) unsigned int*)g,
      (__attribute__((address_space(3))) unsigned int*)l, 16, 0, 0);
}

// ---------------- W conversion fp32 -> bf16, [3][256][256] ----------------
__global__ __launch_bounds__(256) void convert_w_kernel(
    const float* __restrict__ Wb, const float* __restrict__ Wc,
    const float* __restrict__ Wd, unsigned short* __restrict__ Wbf) {
  const int mat = blockIdx.y;
  const float* src = (mat == 0) ? Wb : (mat == 1) ? Wc : Wd;
  int i = (blockIdx.x * 256 + threadIdx.x) * 4;
  float4 v = *reinterpret_cast<const float4*>(src + i);
  uint2 o;
  o.x = pack2(v.x, v.y);
  o.y = pack2(v.z, v.w);
  *reinterpret_cast<uint2*>(Wbf + mat * 65536 + i) = o;
}

// ---------------- fused transpose + 3 projections (coalesced stores) ----------
// tile stride 65 floats: phase-1 col reads step 8 rows -> banks spread 2-way
// (free). Any 16B-aligned stride (64+4k) makes the 8-row step land on ONE
// bank (8-way conflict) -- do not "fix" the pad for b128 writes.
// V epilogue: single round -- waves write their o-quarter into {bounce, xsub}
// (xsub is dead after mat 2's MFMA reads), then one sweep stores both halves.
__global__ __launch_bounds__(256, 2) void fused_proj_kernel(
    const float* __restrict__ x, const unsigned short* __restrict__ Wbf,
    const float* __restrict__ bb, const float* __restrict__ bc,
    const float* __restrict__ bd, unsigned short* __restrict__ Q,
    unsigned short* __restrict__ K, unsigned short* __restrict__ Vt) {
  __shared__ __align__(16) float tile[64][65];   // phase-1 scratch + bounce
  __shared__ __align__(16) char xsub[32768];
  char* bounce = (char*)tile;

  const int tid = threadIdx.x;
  const int wid = tid >> 6, lane = tid & 63;
  const int l31 = lane & 31, hi = lane >> 5;
  const int lt = blockIdx.x, n = blockIdx.y;

  // ---- phase 1: x[n][c][lt*64..] -> bf16 subtiles ----
  #pragma unroll 1
  for (int ct = 0; ct < 4; ++ct) {
    const float* xg = x + ((size_t)(n * CCH + ct * 64)) * NPIX + lt * 64;
    #pragma unroll
    for (int it = 0; it < 4; ++it) {
      int row = (tid >> 4) + it * 16;
      int col = (tid & 15) * 4;
      float4 v = *reinterpret_cast<const float4*>(xg + (size_t)row * NPIX + col);
      tile[row][col] = v.x; tile[row][col + 1] = v.y;
      tile[row][col + 2] = v.z; tile[row][col + 3] = v.w;
    }
    __syncthreads();
    #pragma unroll
    for (int it = 0; it < 2; ++it) {
      int idx = tid + it * 256;
      int l = idx >> 3;
      int ch = (idx & 7) * 8;
      int c = ct * 64 + ch;
      uint4 o;
      o.x = pack2(tile[ch + 0][l], tile[ch + 1][l]);
      o.y = pack2(tile[ch + 2][l], tile[ch + 3][l]);
      o.z = pack2(tile[ch + 4][l], tile[ch + 5][l]);
      o.w = pack2(tile[ch + 6][l], tile[ch + 7][l]);
      int addr = (l >> 5) * 16384 + (c >> 4) * 1024 + ((c >> 3) & 1) * 512 + (l & 31) * 16;
      *reinterpret_cast<uint4*>(xsub + addr) = o;
    }
    __syncthreads();
  }

  // ---- phase 2: wave = o-quarter [wid*64, wid*64+64) ----
  const int o0a = wid * 64, o0b = wid * 64 + 32;
  const size_t pixrow = (size_t)n * NPIX + lt * 64;

  #pragma unroll 1
  for (int mat = 0; mat < 3; ++mat) {
    const unsigned short* W = Wbf + mat * 65536;
    const float* bias = (mat == 0) ? bb : (mat == 1) ? bc : bd;
    f32x16 a00, a01, a10, a11;  // [oi][pix-half]
    #pragma unroll
    for (int e = 0; e < 16; ++e) { a00[e] = 0.f; a01[e] = 0.f; a10[e] = 0.f; a11[e] = 0.f; }
    #pragma unroll
    for (int c0 = 0; c0 < 16; ++c0) {
      bf16x8 x0 = *reinterpret_cast<const bf16x8*>(xsub + c0 * 1024 + lane * 16);
      bf16x8 x1 = *reinterpret_cast<const bf16x8*>(xsub + 16384 + c0 * 1024 + lane * 16);
      bf16x8 w0 = *reinterpret_cast<const bf16x8*>(W + (o0a + l31) * CCH + c0 * 16 + hi * 8);
      bf16x8 w1 = *reinterpret_cast<const bf16x8*>(W + (o0b + l31) * CCH + c0 * 16 + hi * 8);
      if (mat < 2) {
        a00 = __builtin_amdgcn_mfma_f32_32x32x16_bf16(w0, x0, a00, 0, 0, 0);
        a01 = __builtin_amdgcn_mfma_f32_32x32x16_bf16(w0, x1, a01, 0, 0, 0);
        a10 = __builtin_amdgcn_mfma_f32_32x32x16_bf16(w1, x0, a10, 0, 0, 0);
        a11 = __builtin_amdgcn_mfma_f32_32x32x16_bf16(w1, x1, a11, 0, 0, 0);
      } else {
        a00 = __builtin_amdgcn_mfma_f32_32x32x16_bf16(x0, w0, a00, 0, 0, 0);
        a01 = __builtin_amdgcn_mfma_f32_32x32x16_bf16(x1, w0, a01, 0, 0, 0);
        a10 = __builtin_amdgcn_mfma_f32_32x32x16_bf16(x0, w1, a10, 0, 0, 0);
        a11 = __builtin_amdgcn_mfma_f32_32x32x16_bf16(x1, w1, a11, 0, 0, 0);
      }
    }
    if (mat < 2) {
      unsigned short* dst = (mat == 0) ? Q : K;
      #pragma unroll 1
      for (int ph = 0; ph < 2; ++ph) {
        __syncthreads();
        const f32x16& A0 = ph ? a01 : a00;
        const f32x16& A1 = ph ? a11 : a10;
        const int swz = (l31 & 15) << 4;
        #pragma unroll
        for (int r2 = 0; r2 < 8; ++r2) {
          const int r = r2 * 2;
          const int od = (r & 3) + 8 * (r >> 2) + 4 * hi;
          const int oa = o0a + od, ob = o0b + od;
          *reinterpret_cast<unsigned int*>(bounce + ((l31 * 512 + oa * 2) ^ swz)) =
              pack2(A0[r] + bias[oa], A0[r + 1] + bias[oa + 1]);
          *reinterpret_cast<unsigned int*>(bounce + ((l31 * 512 + ob * 2) ^ swz)) =
              pack2(A1[r] + bias[ob], A1[r + 1] + bias[ob + 1]);
        }
        __syncthreads();
        const int dp = tid >> 3, obase = (tid & 7) * 32;
        const int dswz = (dp & 15) << 4;
        char* gout = (char*)(dst + (pixrow + ph * 32 + dp) * CCH + obase);
        #pragma unroll
        for (int k = 0; k < 4; ++k) {
          u32x4 v = *reinterpret_cast<const u32x4*>(
              bounce + ((dp * 512 + obase * 2 + k * 16) ^ dswz));
          *reinterpret_cast<u32x4*>(gout + k * 16) = v;
        }
      }
    } else {
      // ---- V epilogue: single round, both o-halves concurrently ----
      __syncthreads();   // all waves finished xsub MFMA reads; xsub reusable
      {
        char* dstb = (wid >> 1) ? xsub : bounce;
        const int ola = (wid & 1) * 64 + l31;   // o0a + l31 - (wid>>1)*128
        const int olb = ola + 32;
        const float bva = bias[o0a + l31], bvb = bias[o0b + l31];
        const int sza = (ola & 7) << 4, szb = (olb & 7) << 4;
        #pragma unroll
        for (int r2 = 0; r2 < 8; ++r2) {
          const int r = r2 * 2;
          const int pd = (r & 3) + 8 * (r >> 2) + 4 * hi;
          *reinterpret_cast<unsigned int*>(dstb + ((ola * 128 + pd * 2) ^ sza)) =
              pack2(a00[r] + bva, a00[r + 1] + bva);
          *reinterpret_cast<unsigned int*>(dstb + ((ola * 128 + (pd + 32) * 2) ^ sza)) =
              pack2(a01[r] + bva, a01[r + 1] + bva);
          *reinterpret_cast<unsigned int*>(dstb + ((olb * 128 + pd * 2) ^ szb)) =
              pack2(a10[r] + bvb, a10[r + 1] + bvb);
          *reinterpret_cast<unsigned int*>(dstb + ((olb * 128 + (pd + 32) * 2) ^ szb)) =
              pack2(a11[r] + bvb, a11[r + 1] + bvb);
        }
      }
      __syncthreads();
      const int ol = tid >> 1, pb0 = (tid & 1) * 32;
      const int vswz = (ol & 7) << 4;
      #pragma unroll
      for (int os = 0; os < 2; ++os) {
        const char* srcb = os ? xsub : bounce;
        char* gout = (char*)(Vt + ((size_t)(n * CCH + os * 128 + ol)) * NPIX + lt * 64 + pb0);
        #pragma unroll
        for (int k = 0; k < 4; ++k) {
          u32x4 v = *reinterpret_cast<const u32x4*>(
              srcb + ((ol * 128 + pb0 * 2 + k * 16) ^ vswz));
          *reinterpret_cast<u32x4*>(gout + k * 16) = v;
        }
      }
    }
  }
}

// ---------------- attention partial: one j-half per block (plateau-frozen) ----
// 4 waves x 32 q; KVBLK=32, 64 iters, dbuf 2x32KB -> 2 blocks/CU.
// Structural ceiling (R1-R3 falsified: barrier drain, T15 overlap, dep-latency):
// LDS-read demand = waves/CU x 1KB/kv-row (55us @ 8 waves/CU), MFMA 55us,
// VALU ~50us, wall 157us latency-bound at 2 streams/SIMD. More streams needs
// <=128 regs/wave -> q=16/wave -> LDS traffic doubles (~110us). Pinched.
__global__ __launch_bounds__(256, 2) void attn_part_kernel(
    const unsigned short* __restrict__ Q, const unsigned short* __restrict__ K,
    const unsigned short* __restrict__ Vt, unsigned short* __restrict__ Opart,
    float* __restrict__ lsumbuf) {
  __shared__ __align__(16) char smem[65536];

  const int tid = threadIdx.x;
  const int wid = tid >> 6;
  const int lane = tid & 63;
  const int l31 = lane & 31;
  const int hi = lane >> 5;
  const int lofs = lane << 4;
  const int blk = blockIdx.x;
  const int n = blk & 7;
  const int t2 = blk >> 3;
  const int half = t2 & 1;
  const int qb = t2 >> 1;
  const int q0 = qb * 128 + wid * 32;

  const unsigned short* Qg = Q + (size_t)n * NPIX * CCH;
  const char* Kg = (const char*)(K + ((size_t)n * NPIX + half * 2048) * CCH);
  const char* Vg = (const char*)(Vt + (size_t)n * CCH * NPIX + half * 2048);

  bf16x8 qf[16];
  #pragma unroll
  for (int c0 = 0; c0 < 16; ++c0)
    qf[c0] = *reinterpret_cast<const bf16x8*>(
        Qg + (size_t)(q0 + l31) * CCH + c0 * 16 + hi * 8);

  f32x16 oacc[8];
  #pragma unroll
  for (int i = 0; i < 8; ++i)
    #pragma unroll
    for (int e = 0; e < 16; ++e) oacc[i][e] = 0.f;
  float lsum = 0.f;

  const bool isK = wid < 2;
  const char* splane = isK ? Kg : Vg;
  const int sinc = isK ? 32 * 512 : 64;
  int soff[8];
  #pragma unroll
  for (int g = 0; g < 8; ++g) {
    int s = ((wid & 1) << 3) + g;
    if (isK) {
      soff[g] = l31 * 512 + s * 32 + hi * 16;
    } else {
      int cb = s >> 1, kk2 = s & 1;
      soff[g] = (cb * 32 + l31) * 8192 + (kk2 * 16 + hi * 8) * 2;
    }
  }

  auto STAGE = [&](int par, int adv) {
    #pragma unroll
    for (int g = 0; g < 8; ++g)
      gld_lds16(splane + (size_t)soff[g] + (size_t)adv,
                smem + par * 32768 + (((wid << 3) + g) << 10));
  };

  STAGE(0, 0);
  __syncthreads();

  #pragma unroll 1
  for (int t = 0; t < 64; ++t) {
    const int par = t & 1;
    const char* kb = smem + par * 32768;
    const char* vb = kb + 16384;

    f32x16 S;
    #pragma unroll
    for (int e = 0; e < 16; ++e) S[e] = 0.f;
    __builtin_amdgcn_s_setprio(1);
    #pragma unroll
    for (int c0 = 0; c0 < 16; ++c0) {
      bf16x8 kf = *reinterpret_cast<const bf16x8*>(kb + c0 * 1024 + lofs);
      S = __builtin_amdgcn_mfma_f32_32x32x16_bf16(kf, qf[c0], S, 0, 0, 0);
    }
    __builtin_amdgcn_s_setprio(0);

    // prefetch of next tile issued while softmax runs
    if (t < 63) STAGE(par ^ 1, (t + 1) * sinc);

    // ---- fixed-offset softmax: P = exp2(S*log2e - 101), pack via cvt_pk ----
    float rsum = 0.f;
    unsigned int pw[8];
    #pragma unroll
    for (int i = 0; i < 8; ++i) {
      float p0 = exp2f(fmaf(S[2 * i],     1.44269504f, -101.0f));
      float p1 = exp2f(fmaf(S[2 * i + 1], 1.44269504f, -101.0f));
      rsum += p0 + p1;
      unsigned int r;
      asm("v_cvt_pk_bf16_f32 %0, %1, %2" : "=v"(r) : "v"(p0), "v"(p1));
      pw[i] = r;
    }
    lsum += rsum;

    // ---- P re-layout via permlane32_swap ----
    unsigned int s0a = pw[0], s0b = pw[2];
    unsigned int s1a = pw[1], s1b = pw[3];
    unsigned int s2a = pw[4], s2b = pw[6];
    unsigned int s3a = pw[5], s3b = pw[7];
    asm volatile("v_permlane32_swap_b32 %0, %1" : "+v"(s0a), "+v"(s0b));
    asm volatile("v_permlane32_swap_b32 %0, %1" : "+v"(s1a), "+v"(s1b));
    asm volatile("v_permlane32_swap_b32 %0, %1" : "+v"(s2a), "+v"(s2b));
    asm volatile("v_permlane32_swap_b32 %0, %1" : "+v"(s3a), "+v"(s3b));
    u32x4 f0, f1;
    f0[0] = s0a; f0[1] = s1a; f0[2] = s0b; f0[3] = s1b;
    f1[0] = s2a; f1[1] = s3a; f1[2] = s2b; f1[3] = s3b;
    bf16x8 pa0 = __builtin_bit_cast(bf16x8, f0);
    bf16x8 pa1 = __builtin_bit_cast(bf16x8, f1);

    __builtin_amdgcn_s_setprio(1);
    #pragma unroll
    for (int cb = 0; cb < 8; ++cb) {
      bf16x8 v0 = *reinterpret_cast<const bf16x8*>(vb + (cb * 2 + 0) * 1024 + lofs);
      oacc[cb] = __builtin_amdgcn_mfma_f32_32x32x16_bf16(pa0, v0, oacc[cb], 0, 0, 0);
    }
    #pragma unroll
    for (int cb = 0; cb < 8; ++cb) {
      bf16x8 v1 = *reinterpret_cast<const bf16x8*>(vb + (cb * 2 + 1) * 1024 + lofs);
      oacc[cb] = __builtin_amdgcn_mfma_f32_32x32x16_bf16(pa1, v1, oacc[cb], 0, 0, 0);
    }
    __builtin_amdgcn_s_setprio(0);

    __syncthreads();
  }

  lsum += __shfl_xor(lsum, 32);
  char* slab = (char*)Opart + (size_t)blk * 65536;
  #pragma unroll
  for (int cb = 0; cb < 8; ++cb) {
    u32x4 u0, u1;
    u0[0] = pack2(oacc[cb][0],  oacc[cb][1]);
    u0[1] = pack2(oacc[cb][2],  oacc[cb][3]);
    u0[2] = pack2(oacc[cb][4],  oacc[cb][5]);
    u0[3] = pack2(oacc[cb][6],  oacc[cb][7]);
    u1[0] = pack2(oacc[cb][8],  oacc[cb][9]);
    u1[1] = pack2(oacc[cb][10], oacc[cb][11]);
    u1[2] = pack2(oacc[cb][12], oacc[cb][13]);
    u1[3] = pack2(oacc[cb][14], oacc[cb][15]);
    *reinterpret_cast<u32x4*>(slab + (cb * 2 + 0) * 4096 + tid * 16) = u0;
    *reinterpret_cast<u32x4*>(slab + (cb * 2 + 1) * 4096 + tid * 16) = u1;
  }
  if (hi == 0) lsumbuf[blk * 128 + wid * 32 + l31] = lsum;
}

// ---------------- merge halves + normalize + residual + transpose ----------------
// grid 256 = (n, qb); 512 threads (8 waves -> better latency hiding).
// Thread (pr8 = tid>>6): qsub = pr8&3, cb-half = pr8>>2.
__global__ __launch_bounds__(512) void merge_kernel(
    const unsigned short* __restrict__ Opart, const float* __restrict__ lsumbuf,
    const float* __restrict__ x, const float* __restrict__ alpha_p,
    float* __restrict__ out) {
  __shared__ float T[32768];   // [c 0..255][q' 0..127], elem = c*128 + (q'^(c&28))
  __shared__ float Lq[128];

  const int tid = threadIdx.x;
  const int pr8 = tid >> 6;
  const int lane = tid & 63;
  const int l31 = lane & 31;
  const int hi = lane >> 5;
  const int qsub = pr8 & 3;
  const int cbh = pr8 >> 2;
  const int atid = qsub * 64 + lane;    // matching attn-slab thread index
  const int m = blockIdx.x;
  const int n = m & 7;
  const int qb = m >> 3;
  const int blkA = n + 8 * (0 + 2 * qb);
  const int blkB = n + 8 * (1 + 2 * qb);

  if (tid < 128)
    Lq[tid] = alpha_p[0] / (lsumbuf[blkA * 128 + tid] + lsumbuf[blkB * 128 + tid]);
  __syncthreads();

  const char* sa = (const char*)Opart + (size_t)blkA * 65536;
  const char* sb = (const char*)Opart + (size_t)blkB * 65536;

  #pragma unroll
  for (int cbi = 0; cbi < 4; ++cbi) {
    const int cb = cbh * 4 + cbi;
    const int c = cb * 32 + l31;
    const int swz = c & 28;
    #pragma unroll
    for (int h = 0; h < 2; ++h) {
      u32x4 a = *reinterpret_cast<const u32x4*>(sa + (cb * 2 + h) * 4096 + atid * 16);
      u32x4 b = *reinterpret_cast<const u32x4*>(sb + (cb * 2 + h) * 4096 + atid * 16);
      #pragma unroll
      for (int w = 0; w < 4; ++w) {
        const int r = h * 8 + w * 2;
        float v0 = bfu((unsigned short)(a[w] & 0xFFFF)) + bfu((unsigned short)(b[w] & 0xFFFF));
        float v1 = bfu((unsigned short)(a[w] >> 16)) + bfu((unsigned short)(b[w] >> 16));
        const int q0l = qsub * 32 + ((r) & 3) + 8 * ((r) >> 2) + 4 * hi;
        const int q1l = q0l + 1;
        T[c * 128 + (q0l ^ swz)] = v0 * Lq[q0l];
        T[c * 128 + (q1l ^ swz)] = v1 * Lq[q1l];
      }
    }
  }
  __syncthreads();

  // write out: 16 sweeps, 16 c-rows per sweep, float4 per thread
  const int l0 = (tid & 31) * 4;
  #pragma unroll 4
  for (int sw = 0; sw < 16; ++sw) {
    const int c = (tid >> 5) + sw * 16;
    const float* src = &T[c * 128 + (l0 ^ (c & 28))];
    float4 v = *reinterpret_cast<const float4*>(src);
    const size_t g = ((size_t)n * CCH + c) * NPIX + qb * 128 + l0;
    float4 xi = *reinterpret_cast<const float4*>(x + g);
    float4 o;
    o.x = v.x + xi.x; o.y = v.y + xi.y; o.z = v.z + xi.z; o.w = v.w + xi.w;
    *reinterpret_cast<float4*>(out + g) = o;
  }
}

extern "C" void kernel_launch(void* const* d_in, const int* in_sizes, int n_in,
                              void* d_out, int out_size, void* d_ws, size_t ws_size,
                              hipStream_t stream) {
  const float* x  = (const float*)d_in[0];
  const float* Wb = (const float*)d_in[1];
  const float* bb = (const float*)d_in[2];
  const float* Wc = (const float*)d_in[3];
  const float* bc = (const float*)d_in[4];
  const float* Wd = (const float*)d_in[5];
  const float* bd = (const float*)d_in[6];
  const float* alpha = (const float*)d_in[7];
  float* out = (float*)d_out;
  char* ws = (char*)d_ws;

  unsigned short* Wbf   = (unsigned short*)(ws);                //    393,216 B
  unsigned short* Q     = (unsigned short*)(ws + 393216);       // 16,777,216 B
  unsigned short* K     = (unsigned short*)(ws + 17170432);     // 16,777,216 B
  unsigned short* Vt    = (unsigned short*)(ws + 33947648);     // 16,777,216 B
  unsigned short* Opart = (unsigned short*)(ws + 50724864);     // 33,554,432 B
  float*          lsumb = (float*)(ws + 84279296);              //    262,144 B

  convert_w_kernel<<<dim3(64, 3), 256, 0, stream>>>(Wb, Wc, Wd, Wbf);
  fused_proj_kernel<<<dim3(64, 8), 256, 0, stream>>>(x, Wbf, bb, bc, bd, Q, K, Vt);
  attn_part_kernel<<<dim3(512), 256, 0, stream>>>(Q, K, Vt, Opart, lsumb);
  merge_kernel<<<dim3(256), 512, 0, stream>>>(Opart, lsumb, x, alpha, out);
}